// Round 8
// baseline (28017.758 us; speedup 1.0000x reference)
//
#include <hip/hip_runtime.h>
#include <hip/hip_fp16.h>
#include <math.h>

// ChebConv (K=4) GNN head. N=50000, E=800000, F_IN=64, H=128.
// R8 = R4 (best: 232us) + XCD-owned scatter (each epk line / cursor written
// by one XCD only; permuted cursor array) + padded CSR (deg rounded to 4,
// no ragged tails in spmm). MFMA GEMM unchanged.

#define FIN 64
#define HDIM 128

typedef _Float16 half8 __attribute__((ext_vector_type(8)));
typedef float f32x4 __attribute__((ext_vector_type(4)));

union U16 { uint4 u; __half2 h2[4]; half8 h8; };

__global__ void count_deg(const int* __restrict__ row, int* __restrict__ deg, int E) {
    int e = blockIdx.x * blockDim.x + threadIdx.x;
    if (e < E) atomicAdd(&deg[row[e]], 1);
}

__global__ void make_dinv(const int* __restrict__ deg, float* __restrict__ dinv, int n) {
    int i = blockIdx.x * blockDim.x + threadIdx.x;
    if (i < n) {
        int d = deg[i];
        dinv[i] = (d > 0) ? rsqrtf((float)d) : 0.f;
    }
}

// features fp32 -> fp16 rows
__global__ void cvt_feat(const float4* __restrict__ src, uint4* __restrict__ dst, int n8) {
    int i = blockIdx.x * blockDim.x + threadIdx.x;
    if (i >= n8) return;
    float4 a = src[i * 2], b = src[i * 2 + 1];
    U16 v;
    v.h2[0] = __float22half2_rn(make_float2(a.x, a.y));
    v.h2[1] = __float22half2_rn(make_float2(a.z, a.w));
    v.h2[2] = __float22half2_rn(make_float2(b.x, b.y));
    v.h2[3] = __float22half2_rn(make_float2(b.z, b.w));
    dst[i] = v.u;
}

// Pre-swizzle cheb_w (B[256 k][128 h] fp32) into per-lane MFMA B-fragments:
// Bfrag[(kk*8+ht)*64+lane] = 8 halfs B[kk*32+(lane>>4)*8+j][ht*16+(lane&15)]
__global__ void make_bfrag(const float* __restrict__ W, uint4* __restrict__ bfrag) {
    int t = blockIdx.x * blockDim.x + threadIdx.x;   // 0..4095
    if (t >= 8 * 8 * 64) return;
    int lane = t & 63;
    int ht = (t >> 6) & 7;
    int kk = t >> 9;
    int h = ht * 16 + (lane & 15);
    int kb = kk * 32 + (lane >> 4) * 8;
    U16 v;
#pragma unroll
    for (int j = 0; j < 4; ++j) {
        float a = W[(kb + 2 * j) * HDIM + h];
        float b = W[(kb + 2 * j + 1) * HDIM + h];
        v.h2[j] = __float22half2_rn(make_float2(a, b));
    }
    bfrag[t] = v.u;
}

// Per-block exclusive scan over PADDED degrees ((deg+3)&~3) + block totals.
__global__ void scan_local(const int* __restrict__ deg, int* __restrict__ out,
                           int* __restrict__ bsum, int n) {
    __shared__ int buf[1024];
    int tid = threadIdx.x;
    int gid = blockIdx.x * 1024 + tid;
    int v = (gid < n) ? ((deg[gid] + 3) & ~3) : 0;
    int x = v;
    buf[tid] = x;
    __syncthreads();
    for (int off = 1; off < 1024; off <<= 1) {
        int t = (tid >= off) ? buf[tid - off] : 0;
        __syncthreads();
        x += t;
        buf[tid] = x;
        __syncthreads();
    }
    if (gid < n) out[gid] = x - v;
    if (tid == 1023) bsum[blockIdx.x] = x;
}

__global__ void scan_bsums(int* bsum, int nb) {
    if (blockIdx.x == 0 && threadIdx.x == 0) {
        int acc = 0;
        for (int b = 0; b < nb; ++b) { int t = bsum[b]; bsum[b] = acc; acc += t; }
    }
}

// rowptr[i]: padded CSR base. cursor permuted: cur[(i&7)*stride8 + (i>>3)]
// so each XCD's cursors are contiguous (L2-pinned, no cross-XCD lines).
__global__ void scan_finish(int* __restrict__ rowptr, const int* __restrict__ bsum,
                            int* __restrict__ cursor, int n, int stride8, int e_pad) {
    int i = blockIdx.x * blockDim.x + threadIdx.x;
    if (i < n) {
        int v = rowptr[i] + bsum[i >> 10];
        rowptr[i] = v;
        cursor[(i & 7) * stride8 + (i >> 3)] = v;
    } else if (i == n) {
        rowptr[n] = e_pad;
    }
}

// XCD-owned scatter: grid = 8 * ceil(E/256); consecutive blockIdx round-robin
// across XCDs, so xcd = blockIdx&7, e-chunk = blockIdx>>3. Each block filters
// edges whose row%8 == xcd -> every epk line + cursor written by ONE XCD.
__global__ void scatter_xcd(const int* __restrict__ row, const int* __restrict__ col,
                            const float* __restrict__ dinv, int* __restrict__ cursor,
                            int2* __restrict__ epk, int E, int stride8) {
    int xcd = blockIdx.x & 7;
    int e = (blockIdx.x >> 3) * blockDim.x + threadIdx.x;
    if (e < E) {
        int r = row[e];
        if ((r & 7) == xcd) {
            int c = col[e];
            int p = atomicAdd(&cursor[xcd * stride8 + (r >> 3)], 1);
            float w = -dinv[r] * dinv[c];   // L_hat = -D^-1/2 A D^-1/2
            epk[p] = make_int2(c, __float_as_int(w));
        }
    }
}

// 8 rows/wave, 8 lanes/row, 16B (8 halfs) per lane, fp32 accumulate.
// Padded CSR: (e-s)%4 == 0, no tails. Pad slots are (col=0,w=0).
__global__ __launch_bounds__(256) void spmm_h(
        const int* __restrict__ rowptr, const int2* __restrict__ epk,
        const uint4* __restrict__ in8, const uint4* __restrict__ prev8,
        float scale, uint4* __restrict__ out8, int n) {
    int lane = threadIdx.x & 63;
    int wid = (blockIdx.x * blockDim.x + threadIdx.x) >> 6;
    int li = lane & 7, g = lane >> 3;
    int r = wid * 8 + g;
    if (r >= n) return;
    int s = rowptr[r], e = rowptr[r + 1];
    float acc[8];
#pragma unroll
    for (int j = 0; j < 8; ++j) acc[j] = 0.f;
    for (int p = s; p < e; p += 4) {
        int2 m0 = epk[p], m1 = epk[p + 1], m2 = epk[p + 2], m3 = epk[p + 3];
        U16 v0, v1, v2, v3;
        v0.u = in8[(size_t)m0.x * 8 + li];
        v1.u = in8[(size_t)m1.x * 8 + li];
        v2.u = in8[(size_t)m2.x * 8 + li];
        v3.u = in8[(size_t)m3.x * 8 + li];
        float w0 = __int_as_float(m0.y), w1 = __int_as_float(m1.y);
        float w2 = __int_as_float(m2.y), w3 = __int_as_float(m3.y);
#pragma unroll
        for (int j = 0; j < 4; ++j) {
            float2 f0 = __half22float2(v0.h2[j]);
            float2 f1 = __half22float2(v1.h2[j]);
            float2 f2 = __half22float2(v2.h2[j]);
            float2 f3 = __half22float2(v3.h2[j]);
            acc[2 * j]     = fmaf(w0, f0.x, acc[2 * j]);
            acc[2 * j + 1] = fmaf(w0, f0.y, acc[2 * j + 1]);
            acc[2 * j]     = fmaf(w1, f1.x, acc[2 * j]);
            acc[2 * j + 1] = fmaf(w1, f1.y, acc[2 * j + 1]);
            acc[2 * j]     = fmaf(w2, f2.x, acc[2 * j]);
            acc[2 * j + 1] = fmaf(w2, f2.y, acc[2 * j + 1]);
            acc[2 * j]     = fmaf(w3, f3.x, acc[2 * j]);
            acc[2 * j + 1] = fmaf(w3, f3.y, acc[2 * j + 1]);
        }
    }
    float res[8];
    if (prev8) {
        U16 pv;
        pv.u = prev8[(size_t)r * 8 + li];
#pragma unroll
        for (int t = 0; t < 4; ++t) {
            float2 f = __half22float2(pv.h2[t]);
            res[2 * t]     = fmaf(scale, acc[2 * t], -f.x);
            res[2 * t + 1] = fmaf(scale, acc[2 * t + 1], -f.y);
        }
    } else {
#pragma unroll
        for (int j = 0; j < 8; ++j) res[j] = scale * acc[j];
    }
    U16 ru;
#pragma unroll
    for (int t = 0; t < 4; ++t)
        ru.h2[t] = __float22half2_rn(make_float2(res[2 * t], res[2 * t + 1]));
    out8[(size_t)r * 8 + li] = ru.u;
}

__device__ inline float tanh_fast(float x) {
    x = fmaxf(-10.f, fminf(10.f, x));
    float e = __expf(2.f * x);
    return (e - 1.f) / (e + 1.f);
}

// MFMA GEMM + tanh + final dot. Block = 256 thr = 4 waves; wave = 16 nodes x
// 128 h (8 tiles of 16x16, K=32/step, 8 steps over K=256). LDS-free.
__global__ __launch_bounds__(256) void gemm_mfma(
        const uint4* __restrict__ tx0, const uint4* __restrict__ tx1,
        const uint4* __restrict__ tx2, const uint4* __restrict__ tx3,
        const uint4* __restrict__ bfrag,
        const float* __restrict__ cheb_b, const float* __restrict__ fw,
        const float* __restrict__ fb, float* __restrict__ out, int n) {
    int tid = threadIdx.x;
    int lane = tid & 63;
    int wave = tid >> 6;
    int q = lane >> 4, m = lane & 15;
    int node_base = blockIdx.x * 64 + wave * 16;
    int node = node_base + m;
    size_t nd = (node < n) ? (size_t)node : 0;   // clamp; store is guarded

    f32x4 acc[8];
#pragma unroll
    for (int t = 0; t < 8; ++t) acc[t] = (f32x4){0.f, 0.f, 0.f, 0.f};

    const uint4* txs[4] = {tx0, tx1, tx2, tx3};
#pragma unroll
    for (int kk = 0; kk < 8; ++kk) {
        U16 av;
        av.u = txs[kk >> 1][nd * 8 + (kk & 1) * 4 + q];
#pragma unroll
        for (int ht = 0; ht < 8; ++ht) {
            U16 bv;
            bv.u = bfrag[(kk * 8 + ht) * 64 + lane];
            acc[ht] = __builtin_amdgcn_mfma_f32_16x16x32_f16(av.h8, bv.h8, acc[ht], 0, 0, 0);
        }
    }

    float s[4] = {0.f, 0.f, 0.f, 0.f};
#pragma unroll
    for (int ht = 0; ht < 8; ++ht) {
        int h = ht * 16 + m;
        float cb = cheb_b[h];
        float fv = fw[h];
#pragma unroll
        for (int r = 0; r < 4; ++r)
            s[r] = fmaf(tanh_fast(acc[ht][r] + cb), fv, s[r]);
    }
#pragma unroll
    for (int r = 0; r < 4; ++r) {
        for (int msk = 1; msk < 16; msk <<= 1)
            s[r] += __shfl_xor(s[r], msk, 64);
    }
    if (m == 0) {
        float fb0 = fb[0];
#pragma unroll
        for (int r = 0; r < 4; ++r) {
            int o = node_base + q * 4 + r;
            if (o < n) out[o] = s[r] + fb0;
        }
    }
}

extern "C" void kernel_launch(void* const* d_in, const int* in_sizes, int n_in,
                              void* d_out, int out_size, void* d_ws, size_t ws_size,
                              hipStream_t stream) {
    const float* features = (const float*)d_in[0];
    const int*   edge_index = (const int*)d_in[1];
    const float* cheb_w  = (const float*)d_in[2];
    const float* cheb_b  = (const float*)d_in[3];
    const float* final_w = (const float*)d_in[4];
    const float* final_b = (const float*)d_in[5];
    int N = in_sizes[0] / FIN;
    int E = in_sizes[1] / 2;
    const int* row = edge_index;        // edge_index[0, :]
    const int* col = edge_index + E;    // edge_index[1, :]
    int E_pad = E + 4 * N;              // upper bound on padded edge count
    int stride8 = (N + 7) / 8;

    char* p = (char*)d_ws;
    auto alloc = [&](size_t bytes) {
        char* r = p;
        p += (bytes + 255) & ~(size_t)255;
        return r;
    };
    // deg + epk adjacent: one memset zeroes both (epk pad slots = col 0, w 0)
    int*   deg    = (int*)alloc((size_t)N * 4);
    int2*  epk    = (int2*)alloc((size_t)E_pad * 8);
    size_t zero_bytes = (char*)(epk + E_pad) - (char*)deg;
    float* dinv   = (float*)alloc((size_t)N * 4);
    int*   rowptr = (int*)alloc((size_t)(N + 1) * 4);
    int*   cursor = (int*)alloc((size_t)(stride8 * 8) * 4);
    int*   bsum   = (int*)alloc(1024 * 4);
    uint4* feath  = (uint4*)alloc((size_t)N * FIN * 2);   // fp16 rows
    uint4* tx1h   = (uint4*)alloc((size_t)N * FIN * 2);
    uint4* tx2h   = (uint4*)alloc((size_t)N * FIN * 2);
    uint4* tx3h   = (uint4*)alloc((size_t)N * FIN * 2);
    uint4* bfrag  = (uint4*)alloc(4096 * 16);             // 64 KB B fragments

    hipMemsetAsync(deg, 0, zero_bytes, stream);
    count_deg<<<(E + 255) / 256, 256, 0, stream>>>(row, deg, E);
    make_dinv<<<(N + 255) / 256, 256, 0, stream>>>(deg, dinv, N);
    int n8 = N * FIN / 8;
    cvt_feat<<<(n8 + 255) / 256, 256, 0, stream>>>((const float4*)features, feath, n8);
    make_bfrag<<<16, 256, 0, stream>>>(cheb_w, bfrag);
    int nb = (N + 1023) / 1024;
    scan_local<<<nb, 1024, 0, stream>>>(deg, rowptr, bsum, N);
    scan_bsums<<<1, 64, 0, stream>>>(bsum, nb);
    scan_finish<<<(N + 1 + 255) / 256, 256, 0, stream>>>(rowptr, bsum, cursor, N,
                                                         stride8, E_pad);
    int eb = (E + 255) / 256;
    scatter_xcd<<<eb * 8, 256, 0, stream>>>(row, col, dinv, cursor, epk, E, stride8);

    int spmm_blocks = (((N + 7) / 8) * 64 + 255) / 256;
    // Tx1 = L_hat @ x
    spmm_h<<<spmm_blocks, 256, 0, stream>>>(rowptr, epk, feath, nullptr, 1.f, tx1h, N);
    // Tx2 = 2 * L_hat @ Tx1 - Tx0
    spmm_h<<<spmm_blocks, 256, 0, stream>>>(rowptr, epk, tx1h, feath, 2.f, tx2h, N);
    // Tx3 = 2 * L_hat @ Tx2 - Tx1
    spmm_h<<<spmm_blocks, 256, 0, stream>>>(rowptr, epk, tx2h, tx1h, 2.f, tx3h, N);

    gemm_mfma<<<(N + 63) / 64, 256, 0, stream>>>(feath, tx1h, tx2h, tx3h, bfrag,
                                                 cheb_b, final_w, final_b,
                                                 (float*)d_out, N);
}

// Round 9
// 230.949 us; speedup vs baseline: 121.3159x; 121.3159x over previous
//
#include <hip/hip_runtime.h>
#include <hip/hip_fp16.h>
#include <math.h>

// ChebConv (K=4) GNN head. N=50000, E=800000, F_IN=64, H=128.
// R9 = R8 with the rowptr[N] bug fixed (was E_pad upper bound -> one wave
// serially scanned ~125k phantom pad edges; now exact padded total).
// XCD-owned scatter + permuted cursors + padded CSR + R4 SPMM + MFMA GEMM.

#define FIN 64
#define HDIM 128

typedef _Float16 half8 __attribute__((ext_vector_type(8)));
typedef float f32x4 __attribute__((ext_vector_type(4)));

union U16 { uint4 u; __half2 h2[4]; half8 h8; };

__global__ void count_deg(const int* __restrict__ row, int* __restrict__ deg, int E) {
    int e = blockIdx.x * blockDim.x + threadIdx.x;
    if (e < E) atomicAdd(&deg[row[e]], 1);
}

__global__ void make_dinv(const int* __restrict__ deg, float* __restrict__ dinv, int n) {
    int i = blockIdx.x * blockDim.x + threadIdx.x;
    if (i < n) {
        int d = deg[i];
        dinv[i] = (d > 0) ? rsqrtf((float)d) : 0.f;
    }
}

// features fp32 -> fp16 rows
__global__ void cvt_feat(const float4* __restrict__ src, uint4* __restrict__ dst, int n8) {
    int i = blockIdx.x * blockDim.x + threadIdx.x;
    if (i >= n8) return;
    float4 a = src[i * 2], b = src[i * 2 + 1];
    U16 v;
    v.h2[0] = __float22half2_rn(make_float2(a.x, a.y));
    v.h2[1] = __float22half2_rn(make_float2(a.z, a.w));
    v.h2[2] = __float22half2_rn(make_float2(b.x, b.y));
    v.h2[3] = __float22half2_rn(make_float2(b.z, b.w));
    dst[i] = v.u;
}

// Pre-swizzle cheb_w (B[256 k][128 h] fp32) into per-lane MFMA B-fragments:
// Bfrag[(kk*8+ht)*64+lane] = 8 halfs B[kk*32+(lane>>4)*8+j][ht*16+(lane&15)]
__global__ void make_bfrag(const float* __restrict__ W, uint4* __restrict__ bfrag) {
    int t = blockIdx.x * blockDim.x + threadIdx.x;   // 0..4095
    if (t >= 8 * 8 * 64) return;
    int lane = t & 63;
    int ht = (t >> 6) & 7;
    int kk = t >> 9;
    int h = ht * 16 + (lane & 15);
    int kb = kk * 32 + (lane >> 4) * 8;
    U16 v;
#pragma unroll
    for (int j = 0; j < 4; ++j) {
        float a = W[(kb + 2 * j) * HDIM + h];
        float b = W[(kb + 2 * j + 1) * HDIM + h];
        v.h2[j] = __float22half2_rn(make_float2(a, b));
    }
    bfrag[t] = v.u;
}

// Per-block exclusive scan over PADDED degrees ((deg+3)&~3) + block totals.
__global__ void scan_local(const int* __restrict__ deg, int* __restrict__ out,
                           int* __restrict__ bsum, int n) {
    __shared__ int buf[1024];
    int tid = threadIdx.x;
    int gid = blockIdx.x * 1024 + tid;
    int v = (gid < n) ? ((deg[gid] + 3) & ~3) : 0;
    int x = v;
    buf[tid] = x;
    __syncthreads();
    for (int off = 1; off < 1024; off <<= 1) {
        int t = (tid >= off) ? buf[tid - off] : 0;
        __syncthreads();
        x += t;
        buf[tid] = x;
        __syncthreads();
    }
    if (gid < n) out[gid] = x - v;
    if (tid == 1023) bsum[blockIdx.x] = x;
}

__global__ void scan_bsums(int* bsum, int nb) {
    if (blockIdx.x == 0 && threadIdx.x == 0) {
        int acc = 0;
        for (int b = 0; b < nb; ++b) { int t = bsum[b]; bsum[b] = acc; acc += t; }
    }
}

// rowptr[i]: padded CSR base. cursor permuted: cur[(i&7)*stride8 + (i>>3)]
// so each XCD's cursors are contiguous. rowptr[n] = EXACT padded total
// (rowptr[n-1] + padded deg[n-1]) -- R8's bug was using the E+4N bound.
__global__ void scan_finish(int* __restrict__ rowptr, const int* __restrict__ bsum,
                            const int* __restrict__ deg, int* __restrict__ cursor,
                            int n, int stride8) {
    int i = blockIdx.x * blockDim.x + threadIdx.x;
    if (i < n) {
        int v = rowptr[i] + bsum[i >> 10];
        rowptr[i] = v;
        cursor[(i & 7) * stride8 + (i >> 3)] = v;
        if (i == n - 1) rowptr[n] = v + ((deg[i] + 3) & ~3);
    }
}

// XCD-owned scatter: grid = 8 * ceil(E/256); consecutive blockIdx round-robin
// across XCDs, so xcd = blockIdx&7, e-chunk = blockIdx>>3. Each block filters
// edges whose row%8 == xcd -> every epk line + cursor written by ONE XCD.
__global__ void scatter_xcd(const int* __restrict__ row, const int* __restrict__ col,
                            const float* __restrict__ dinv, int* __restrict__ cursor,
                            int2* __restrict__ epk, int E, int stride8) {
    int xcd = blockIdx.x & 7;
    int e = (blockIdx.x >> 3) * blockDim.x + threadIdx.x;
    if (e < E) {
        int r = row[e];
        if ((r & 7) == xcd) {
            int c = col[e];
            int p = atomicAdd(&cursor[xcd * stride8 + (r >> 3)], 1);
            float w = -dinv[r] * dinv[c];   // L_hat = -D^-1/2 A D^-1/2
            epk[p] = make_int2(c, __float_as_int(w));
        }
    }
}

// 8 rows/wave, 8 lanes/row, 16B (8 halfs) per lane, fp32 accumulate.
// Padded CSR: (e-s)%4 == 0, no tails. Pad slots are (col=0,w=0).
__global__ __launch_bounds__(256) void spmm_h(
        const int* __restrict__ rowptr, const int2* __restrict__ epk,
        const uint4* __restrict__ in8, const uint4* __restrict__ prev8,
        float scale, uint4* __restrict__ out8, int n) {
    int lane = threadIdx.x & 63;
    int wid = (blockIdx.x * blockDim.x + threadIdx.x) >> 6;
    int li = lane & 7, g = lane >> 3;
    int r = wid * 8 + g;
    if (r >= n) return;
    int s = rowptr[r], e = rowptr[r + 1];
    float acc[8];
#pragma unroll
    for (int j = 0; j < 8; ++j) acc[j] = 0.f;
    for (int p = s; p < e; p += 4) {
        int2 m0 = epk[p], m1 = epk[p + 1], m2 = epk[p + 2], m3 = epk[p + 3];
        U16 v0, v1, v2, v3;
        v0.u = in8[(size_t)m0.x * 8 + li];
        v1.u = in8[(size_t)m1.x * 8 + li];
        v2.u = in8[(size_t)m2.x * 8 + li];
        v3.u = in8[(size_t)m3.x * 8 + li];
        float w0 = __int_as_float(m0.y), w1 = __int_as_float(m1.y);
        float w2 = __int_as_float(m2.y), w3 = __int_as_float(m3.y);
#pragma unroll
        for (int j = 0; j < 4; ++j) {
            float2 f0 = __half22float2(v0.h2[j]);
            float2 f1 = __half22float2(v1.h2[j]);
            float2 f2 = __half22float2(v2.h2[j]);
            float2 f3 = __half22float2(v3.h2[j]);
            acc[2 * j]     = fmaf(w0, f0.x, acc[2 * j]);
            acc[2 * j + 1] = fmaf(w0, f0.y, acc[2 * j + 1]);
            acc[2 * j]     = fmaf(w1, f1.x, acc[2 * j]);
            acc[2 * j + 1] = fmaf(w1, f1.y, acc[2 * j + 1]);
            acc[2 * j]     = fmaf(w2, f2.x, acc[2 * j]);
            acc[2 * j + 1] = fmaf(w2, f2.y, acc[2 * j + 1]);
            acc[2 * j]     = fmaf(w3, f3.x, acc[2 * j]);
            acc[2 * j + 1] = fmaf(w3, f3.y, acc[2 * j + 1]);
        }
    }
    float res[8];
    if (prev8) {
        U16 pv;
        pv.u = prev8[(size_t)r * 8 + li];
#pragma unroll
        for (int t = 0; t < 4; ++t) {
            float2 f = __half22float2(pv.h2[t]);
            res[2 * t]     = fmaf(scale, acc[2 * t], -f.x);
            res[2 * t + 1] = fmaf(scale, acc[2 * t + 1], -f.y);
        }
    } else {
#pragma unroll
        for (int j = 0; j < 8; ++j) res[j] = scale * acc[j];
    }
    U16 ru;
#pragma unroll
    for (int t = 0; t < 4; ++t)
        ru.h2[t] = __float22half2_rn(make_float2(res[2 * t], res[2 * t + 1]));
    out8[(size_t)r * 8 + li] = ru.u;
}

__device__ inline float tanh_fast(float x) {
    x = fmaxf(-10.f, fminf(10.f, x));
    float e = __expf(2.f * x);
    return (e - 1.f) / (e + 1.f);
}

// MFMA GEMM + tanh + final dot. Block = 256 thr = 4 waves; wave = 16 nodes x
// 128 h (8 tiles of 16x16, K=32/step, 8 steps over K=256). LDS-free.
__global__ __launch_bounds__(256) void gemm_mfma(
        const uint4* __restrict__ tx0, const uint4* __restrict__ tx1,
        const uint4* __restrict__ tx2, const uint4* __restrict__ tx3,
        const uint4* __restrict__ bfrag,
        const float* __restrict__ cheb_b, const float* __restrict__ fw,
        const float* __restrict__ fb, float* __restrict__ out, int n) {
    int tid = threadIdx.x;
    int lane = tid & 63;
    int wave = tid >> 6;
    int q = lane >> 4, m = lane & 15;
    int node_base = blockIdx.x * 64 + wave * 16;
    int node = node_base + m;
    size_t nd = (node < n) ? (size_t)node : 0;   // clamp; store is guarded

    f32x4 acc[8];
#pragma unroll
    for (int t = 0; t < 8; ++t) acc[t] = (f32x4){0.f, 0.f, 0.f, 0.f};

    const uint4* txs[4] = {tx0, tx1, tx2, tx3};
#pragma unroll
    for (int kk = 0; kk < 8; ++kk) {
        U16 av;
        av.u = txs[kk >> 1][nd * 8 + (kk & 1) * 4 + q];
#pragma unroll
        for (int ht = 0; ht < 8; ++ht) {
            U16 bv;
            bv.u = bfrag[(kk * 8 + ht) * 64 + lane];
            acc[ht] = __builtin_amdgcn_mfma_f32_16x16x32_f16(av.h8, bv.h8, acc[ht], 0, 0, 0);
        }
    }

    float s[4] = {0.f, 0.f, 0.f, 0.f};
#pragma unroll
    for (int ht = 0; ht < 8; ++ht) {
        int h = ht * 16 + m;
        float cb = cheb_b[h];
        float fv = fw[h];
#pragma unroll
        for (int r = 0; r < 4; ++r)
            s[r] = fmaf(tanh_fast(acc[ht][r] + cb), fv, s[r]);
    }
#pragma unroll
    for (int r = 0; r < 4; ++r) {
        for (int msk = 1; msk < 16; msk <<= 1)
            s[r] += __shfl_xor(s[r], msk, 64);
    }
    if (m == 0) {
        float fb0 = fb[0];
#pragma unroll
        for (int r = 0; r < 4; ++r) {
            int o = node_base + q * 4 + r;
            if (o < n) out[o] = s[r] + fb0;
        }
    }
}

extern "C" void kernel_launch(void* const* d_in, const int* in_sizes, int n_in,
                              void* d_out, int out_size, void* d_ws, size_t ws_size,
                              hipStream_t stream) {
    const float* features = (const float*)d_in[0];
    const int*   edge_index = (const int*)d_in[1];
    const float* cheb_w  = (const float*)d_in[2];
    const float* cheb_b  = (const float*)d_in[3];
    const float* final_w = (const float*)d_in[4];
    const float* final_b = (const float*)d_in[5];
    int N = in_sizes[0] / FIN;
    int E = in_sizes[1] / 2;
    const int* row = edge_index;        // edge_index[0, :]
    const int* col = edge_index + E;    // edge_index[1, :]
    int E_pad = E + 4 * N;              // allocation bound on padded edges
    int stride8 = (N + 7) / 8;

    char* p = (char*)d_ws;
    auto alloc = [&](size_t bytes) {
        char* r = p;
        p += (bytes + 255) & ~(size_t)255;
        return r;
    };
    // deg + epk adjacent: one memset zeroes both (epk pad slots = col 0, w 0)
    int*   deg    = (int*)alloc((size_t)N * 4);
    int2*  epk    = (int2*)alloc((size_t)E_pad * 8);
    size_t zero_bytes = (char*)(epk + E_pad) - (char*)deg;
    float* dinv   = (float*)alloc((size_t)N * 4);
    int*   rowptr = (int*)alloc((size_t)(N + 1) * 4);
    int*   cursor = (int*)alloc((size_t)(stride8 * 8) * 4);
    int*   bsum   = (int*)alloc(1024 * 4);
    uint4* feath  = (uint4*)alloc((size_t)N * FIN * 2);   // fp16 rows
    uint4* tx1h   = (uint4*)alloc((size_t)N * FIN * 2);
    uint4* tx2h   = (uint4*)alloc((size_t)N * FIN * 2);
    uint4* tx3h   = (uint4*)alloc((size_t)N * FIN * 2);
    uint4* bfrag  = (uint4*)alloc(4096 * 16);             // 64 KB B fragments

    hipMemsetAsync(deg, 0, zero_bytes, stream);
    count_deg<<<(E + 255) / 256, 256, 0, stream>>>(row, deg, E);
    make_dinv<<<(N + 255) / 256, 256, 0, stream>>>(deg, dinv, N);
    int n8 = N * FIN / 8;
    cvt_feat<<<(n8 + 255) / 256, 256, 0, stream>>>((const float4*)features, feath, n8);
    make_bfrag<<<16, 256, 0, stream>>>(cheb_w, bfrag);
    int nb = (N + 1023) / 1024;
    scan_local<<<nb, 1024, 0, stream>>>(deg, rowptr, bsum, N);
    scan_bsums<<<1, 64, 0, stream>>>(bsum, nb);
    scan_finish<<<(N + 255) / 256, 256, 0, stream>>>(rowptr, bsum, deg, cursor, N, stride8);
    int eb = (E + 255) / 256;
    scatter_xcd<<<eb * 8, 256, 0, stream>>>(row, col, dinv, cursor, epk, E, stride8);

    int spmm_blocks = (((N + 7) / 8) * 64 + 255) / 256;
    // Tx1 = L_hat @ x
    spmm_h<<<spmm_blocks, 256, 0, stream>>>(rowptr, epk, feath, nullptr, 1.f, tx1h, N);
    // Tx2 = 2 * L_hat @ Tx1 - Tx0
    spmm_h<<<spmm_blocks, 256, 0, stream>>>(rowptr, epk, tx1h, feath, 2.f, tx2h, N);
    // Tx3 = 2 * L_hat @ Tx2 - Tx1
    spmm_h<<<spmm_blocks, 256, 0, stream>>>(rowptr, epk, tx2h, tx1h, 2.f, tx3h, N);

    gemm_mfma<<<(N + 63) / 64, 256, 0, stream>>>(feath, tx1h, tx2h, tx3h, bfrag,
                                                 cheb_b, final_w, final_b,
                                                 (float*)d_out, N);
}

// Round 10
// 217.019 us; speedup vs baseline: 129.1025x; 1.0642x over previous
//
#include <hip/hip_runtime.h>
#include <hip/hip_fp16.h>
#include <math.h>

// ChebConv (K=4) GNN head. N=50000, E=800000, F_IN=64, H=128.
// R10 = R9 + software-pipelined SPMM (epk descriptors prefetched one
// iteration ahead; prev-row load hoisted) + wave-parallel scan_bsums.
// SPMM is latency-bound (R8 counters: 34MB fetch = ~6us HBM for 35us kernel).

#define FIN 64
#define HDIM 128

typedef _Float16 half8 __attribute__((ext_vector_type(8)));
typedef float f32x4 __attribute__((ext_vector_type(4)));

union U16 { uint4 u; __half2 h2[4]; half8 h8; };

__global__ void count_deg(const int* __restrict__ row, int* __restrict__ deg, int E) {
    int e = blockIdx.x * blockDim.x + threadIdx.x;
    if (e < E) atomicAdd(&deg[row[e]], 1);
}

__global__ void make_dinv(const int* __restrict__ deg, float* __restrict__ dinv, int n) {
    int i = blockIdx.x * blockDim.x + threadIdx.x;
    if (i < n) {
        int d = deg[i];
        dinv[i] = (d > 0) ? rsqrtf((float)d) : 0.f;
    }
}

// features fp32 -> fp16 rows
__global__ void cvt_feat(const float4* __restrict__ src, uint4* __restrict__ dst, int n8) {
    int i = blockIdx.x * blockDim.x + threadIdx.x;
    if (i >= n8) return;
    float4 a = src[i * 2], b = src[i * 2 + 1];
    U16 v;
    v.h2[0] = __float22half2_rn(make_float2(a.x, a.y));
    v.h2[1] = __float22half2_rn(make_float2(a.z, a.w));
    v.h2[2] = __float22half2_rn(make_float2(b.x, b.y));
    v.h2[3] = __float22half2_rn(make_float2(b.z, b.w));
    dst[i] = v.u;
}

// Pre-swizzle cheb_w (B[256 k][128 h] fp32) into per-lane MFMA B-fragments:
// Bfrag[(kk*8+ht)*64+lane] = 8 halfs B[kk*32+(lane>>4)*8+j][ht*16+(lane&15)]
__global__ void make_bfrag(const float* __restrict__ W, uint4* __restrict__ bfrag) {
    int t = blockIdx.x * blockDim.x + threadIdx.x;   // 0..4095
    if (t >= 8 * 8 * 64) return;
    int lane = t & 63;
    int ht = (t >> 6) & 7;
    int kk = t >> 9;
    int h = ht * 16 + (lane & 15);
    int kb = kk * 32 + (lane >> 4) * 8;
    U16 v;
#pragma unroll
    for (int j = 0; j < 4; ++j) {
        float a = W[(kb + 2 * j) * HDIM + h];
        float b = W[(kb + 2 * j + 1) * HDIM + h];
        v.h2[j] = __float22half2_rn(make_float2(a, b));
    }
    bfrag[t] = v.u;
}

// Per-block exclusive scan over PADDED degrees ((deg+3)&~3) + block totals.
__global__ void scan_local(const int* __restrict__ deg, int* __restrict__ out,
                           int* __restrict__ bsum, int n) {
    __shared__ int buf[1024];
    int tid = threadIdx.x;
    int gid = blockIdx.x * 1024 + tid;
    int v = (gid < n) ? ((deg[gid] + 3) & ~3) : 0;
    int x = v;
    buf[tid] = x;
    __syncthreads();
    for (int off = 1; off < 1024; off <<= 1) {
        int t = (tid >= off) ? buf[tid - off] : 0;
        __syncthreads();
        x += t;
        buf[tid] = x;
        __syncthreads();
    }
    if (gid < n) out[gid] = x - v;
    if (tid == 1023) bsum[blockIdx.x] = x;
}

// Wave-parallel exclusive scan of block sums (was a serial 1-thread loop).
__global__ void scan_bsums(int* bsum, int nb) {
    int lane = threadIdx.x;           // 64 threads
    int carry = 0;
    for (int base = 0; base < nb; base += 64) {
        int i = base + lane;
        int v = (i < nb) ? bsum[i] : 0;
        int x = v;
        for (int off = 1; off < 64; off <<= 1) {
            int t = __shfl_up(x, off, 64);
            if (lane >= off) x += t;
        }
        if (i < nb) bsum[i] = carry + x - v;   // exclusive
        carry += __shfl(x, 63, 64);
    }
}

// rowptr[i]: padded CSR base. cursor permuted: cur[(i&7)*stride8 + (i>>3)]
// so each XCD's cursors are contiguous. rowptr[n] = EXACT padded total.
__global__ void scan_finish(int* __restrict__ rowptr, const int* __restrict__ bsum,
                            const int* __restrict__ deg, int* __restrict__ cursor,
                            int n, int stride8) {
    int i = blockIdx.x * blockDim.x + threadIdx.x;
    if (i < n) {
        int v = rowptr[i] + bsum[i >> 10];
        rowptr[i] = v;
        cursor[(i & 7) * stride8 + (i >> 3)] = v;
        if (i == n - 1) rowptr[n] = v + ((deg[i] + 3) & ~3);
    }
}

// XCD-owned scatter: grid = 8 * ceil(E/256); xcd = blockIdx&7 (round-robin
// heuristic). Each block filters edges with row%8 == xcd -> every epk line +
// cursor written by ONE XCD.
__global__ void scatter_xcd(const int* __restrict__ row, const int* __restrict__ col,
                            const float* __restrict__ dinv, int* __restrict__ cursor,
                            int2* __restrict__ epk, int E, int stride8) {
    int xcd = blockIdx.x & 7;
    int e = (blockIdx.x >> 3) * blockDim.x + threadIdx.x;
    if (e < E) {
        int r = row[e];
        if ((r & 7) == xcd) {
            int c = col[e];
            int p = atomicAdd(&cursor[xcd * stride8 + (r >> 3)], 1);
            float w = -dinv[r] * dinv[c];   // L_hat = -D^-1/2 A D^-1/2
            epk[p] = make_int2(c, __float_as_int(w));
        }
    }
}

// 8 rows/wave, 8 lanes/row, 16B (8 halfs) per lane, fp32 accumulate.
// Padded CSR: (e-s)%4 == 0, no tails; pad slots (col=0,w=0).
// Software pipeline: next iteration's epk descriptors load while current
// gathers are in flight; prev-row load hoisted above the loop.
__global__ __launch_bounds__(256) void spmm_h(
        const int* __restrict__ rowptr, const int2* __restrict__ epk,
        const uint4* __restrict__ in8, const uint4* __restrict__ prev8,
        float scale, uint4* __restrict__ out8, int n) {
    int lane = threadIdx.x & 63;
    int wid = (blockIdx.x * blockDim.x + threadIdx.x) >> 6;
    int li = lane & 7, g = lane >> 3;
    int r = wid * 8 + g;
    if (r >= n) return;
    int s = rowptr[r], e = rowptr[r + 1];

    U16 pv;
    if (prev8) pv.u = prev8[(size_t)r * 8 + li];   // in flight across the loop

    float acc[8];
#pragma unroll
    for (int j = 0; j < 8; ++j) acc[j] = 0.f;

    if (s < e) {
        int2 m[4];
#pragma unroll
        for (int j = 0; j < 4; ++j) m[j] = epk[s + j];
        int p = s;
        for (;;) {
            U16 v0, v1, v2, v3;
            v0.u = in8[(size_t)m[0].x * 8 + li];
            v1.u = in8[(size_t)m[1].x * 8 + li];
            v2.u = in8[(size_t)m[2].x * 8 + li];
            v3.u = in8[(size_t)m[3].x * 8 + li];
            float w0 = __int_as_float(m[0].y), w1 = __int_as_float(m[1].y);
            float w2 = __int_as_float(m[2].y), w3 = __int_as_float(m[3].y);
            p += 4;
            bool more = p < e;
            if (more) {
#pragma unroll
                for (int j = 0; j < 4; ++j) m[j] = epk[p + j];   // prefetch
            }
#pragma unroll
            for (int j = 0; j < 4; ++j) {
                float2 f0 = __half22float2(v0.h2[j]);
                float2 f1 = __half22float2(v1.h2[j]);
                float2 f2 = __half22float2(v2.h2[j]);
                float2 f3 = __half22float2(v3.h2[j]);
                acc[2 * j]     = fmaf(w0, f0.x, acc[2 * j]);
                acc[2 * j + 1] = fmaf(w0, f0.y, acc[2 * j + 1]);
                acc[2 * j]     = fmaf(w1, f1.x, acc[2 * j]);
                acc[2 * j + 1] = fmaf(w1, f1.y, acc[2 * j + 1]);
                acc[2 * j]     = fmaf(w2, f2.x, acc[2 * j]);
                acc[2 * j + 1] = fmaf(w2, f2.y, acc[2 * j + 1]);
                acc[2 * j]     = fmaf(w3, f3.x, acc[2 * j]);
                acc[2 * j + 1] = fmaf(w3, f3.y, acc[2 * j + 1]);
            }
            if (!more) break;
        }
    }

    float res[8];
    if (prev8) {
#pragma unroll
        for (int t = 0; t < 4; ++t) {
            float2 f = __half22float2(pv.h2[t]);
            res[2 * t]     = fmaf(scale, acc[2 * t], -f.x);
            res[2 * t + 1] = fmaf(scale, acc[2 * t + 1], -f.y);
        }
    } else {
#pragma unroll
        for (int j = 0; j < 8; ++j) res[j] = scale * acc[j];
    }
    U16 ru;
#pragma unroll
    for (int t = 0; t < 4; ++t)
        ru.h2[t] = __float22half2_rn(make_float2(res[2 * t], res[2 * t + 1]));
    out8[(size_t)r * 8 + li] = ru.u;
}

__device__ inline float tanh_fast(float x) {
    x = fmaxf(-10.f, fminf(10.f, x));
    float e = __expf(2.f * x);
    return (e - 1.f) / (e + 1.f);
}

// MFMA GEMM + tanh + final dot. Block = 256 thr = 4 waves; wave = 16 nodes x
// 128 h (8 tiles of 16x16, K=32/step, 8 steps over K=256). LDS-free.
__global__ __launch_bounds__(256) void gemm_mfma(
        const uint4* __restrict__ tx0, const uint4* __restrict__ tx1,
        const uint4* __restrict__ tx2, const uint4* __restrict__ tx3,
        const uint4* __restrict__ bfrag,
        const float* __restrict__ cheb_b, const float* __restrict__ fw,
        const float* __restrict__ fb, float* __restrict__ out, int n) {
    int tid = threadIdx.x;
    int lane = tid & 63;
    int wave = tid >> 6;
    int q = lane >> 4, m = lane & 15;
    int node_base = blockIdx.x * 64 + wave * 16;
    int node = node_base + m;
    size_t nd = (node < n) ? (size_t)node : 0;   // clamp; store is guarded

    f32x4 acc[8];
#pragma unroll
    for (int t = 0; t < 8; ++t) acc[t] = (f32x4){0.f, 0.f, 0.f, 0.f};

    const uint4* txs[4] = {tx0, tx1, tx2, tx3};
#pragma unroll
    for (int kk = 0; kk < 8; ++kk) {
        U16 av;
        av.u = txs[kk >> 1][nd * 8 + (kk & 1) * 4 + q];
#pragma unroll
        for (int ht = 0; ht < 8; ++ht) {
            U16 bv;
            bv.u = bfrag[(kk * 8 + ht) * 64 + lane];
            acc[ht] = __builtin_amdgcn_mfma_f32_16x16x32_f16(av.h8, bv.h8, acc[ht], 0, 0, 0);
        }
    }

    float s[4] = {0.f, 0.f, 0.f, 0.f};
#pragma unroll
    for (int ht = 0; ht < 8; ++ht) {
        int h = ht * 16 + m;
        float cb = cheb_b[h];
        float fv = fw[h];
#pragma unroll
        for (int r = 0; r < 4; ++r)
            s[r] = fmaf(tanh_fast(acc[ht][r] + cb), fv, s[r]);
    }
#pragma unroll
    for (int r = 0; r < 4; ++r) {
        for (int msk = 1; msk < 16; msk <<= 1)
            s[r] += __shfl_xor(s[r], msk, 64);
    }
    if (m == 0) {
        float fb0 = fb[0];
#pragma unroll
        for (int r = 0; r < 4; ++r) {
            int o = node_base + q * 4 + r;
            if (o < n) out[o] = s[r] + fb0;
        }
    }
}

extern "C" void kernel_launch(void* const* d_in, const int* in_sizes, int n_in,
                              void* d_out, int out_size, void* d_ws, size_t ws_size,
                              hipStream_t stream) {
    const float* features = (const float*)d_in[0];
    const int*   edge_index = (const int*)d_in[1];
    const float* cheb_w  = (const float*)d_in[2];
    const float* cheb_b  = (const float*)d_in[3];
    const float* final_w = (const float*)d_in[4];
    const float* final_b = (const float*)d_in[5];
    int N = in_sizes[0] / FIN;
    int E = in_sizes[1] / 2;
    const int* row = edge_index;        // edge_index[0, :]
    const int* col = edge_index + E;    // edge_index[1, :]
    int E_pad = E + 4 * N;              // allocation bound on padded edges
    int stride8 = (N + 7) / 8;

    char* p = (char*)d_ws;
    auto alloc = [&](size_t bytes) {
        char* r = p;
        p += (bytes + 255) & ~(size_t)255;
        return r;
    };
    // deg + epk adjacent: one memset zeroes both (epk pad slots = col 0, w 0)
    int*   deg    = (int*)alloc((size_t)N * 4);
    int2*  epk    = (int2*)alloc((size_t)E_pad * 8);
    size_t zero_bytes = (char*)(epk + E_pad) - (char*)deg;
    float* dinv   = (float*)alloc((size_t)N * 4);
    int*   rowptr = (int*)alloc((size_t)(N + 1) * 4);
    int*   cursor = (int*)alloc((size_t)(stride8 * 8) * 4);
    int*   bsum   = (int*)alloc(1024 * 4);
    uint4* feath  = (uint4*)alloc((size_t)N * FIN * 2);   // fp16 rows
    uint4* tx1h   = (uint4*)alloc((size_t)N * FIN * 2);
    uint4* tx2h   = (uint4*)alloc((size_t)N * FIN * 2);
    uint4* tx3h   = (uint4*)alloc((size_t)N * FIN * 2);
    uint4* bfrag  = (uint4*)alloc(4096 * 16);             // 64 KB B fragments

    hipMemsetAsync(deg, 0, zero_bytes, stream);
    count_deg<<<(E + 255) / 256, 256, 0, stream>>>(row, deg, E);
    make_dinv<<<(N + 255) / 256, 256, 0, stream>>>(deg, dinv, N);
    int n8 = N * FIN / 8;
    cvt_feat<<<(n8 + 255) / 256, 256, 0, stream>>>((const float4*)features, feath, n8);
    make_bfrag<<<16, 256, 0, stream>>>(cheb_w, bfrag);
    int nb = (N + 1023) / 1024;
    scan_local<<<nb, 1024, 0, stream>>>(deg, rowptr, bsum, N);
    scan_bsums<<<1, 64, 0, stream>>>(bsum, nb);
    scan_finish<<<(N + 255) / 256, 256, 0, stream>>>(rowptr, bsum, deg, cursor, N, stride8);
    int eb = (E + 255) / 256;
    scatter_xcd<<<eb * 8, 256, 0, stream>>>(row, col, dinv, cursor, epk, E, stride8);

    int spmm_blocks = (((N + 7) / 8) * 64 + 255) / 256;
    // Tx1 = L_hat @ x
    spmm_h<<<spmm_blocks, 256, 0, stream>>>(rowptr, epk, feath, nullptr, 1.f, tx1h, N);
    // Tx2 = 2 * L_hat @ Tx1 - Tx0
    spmm_h<<<spmm_blocks, 256, 0, stream>>>(rowptr, epk, tx1h, feath, 2.f, tx2h, N);
    // Tx3 = 2 * L_hat @ Tx2 - Tx1
    spmm_h<<<spmm_blocks, 256, 0, stream>>>(rowptr, epk, tx2h, tx1h, 2.f, tx3h, N);

    gemm_mfma<<<(N + 63) / 64, 256, 0, stream>>>(feath, tx1h, tx2h, tx3h, bfrag,
                                                 cheb_b, final_w, final_b,
                                                 (float*)d_out, N);
}

// Round 11
// 215.985 us; speedup vs baseline: 129.7209x; 1.0048x over previous
//
#include <hip/hip_runtime.h>
#include <hip/hip_fp16.h>
#include <math.h>

// ChebConv (K=4) GNN head. N=50000, E=800000, F_IN=64, H=128.
// R11 = R10 + gather double-buffering in SPMM (desc prefetch depth 2, gather
// depth 1: iter i's accumulate overlaps iter i+1's gathers) + make_dinv
// folded into scan_local.

#define FIN 64
#define HDIM 128

typedef _Float16 half8 __attribute__((ext_vector_type(8)));
typedef float f32x4 __attribute__((ext_vector_type(4)));

union U16 { uint4 u; __half2 h2[4]; half8 h8; };

__global__ void count_deg(const int* __restrict__ row, int* __restrict__ deg, int E) {
    int e = blockIdx.x * blockDim.x + threadIdx.x;
    if (e < E) atomicAdd(&deg[row[e]], 1);
}

// features fp32 -> fp16 rows
__global__ void cvt_feat(const float4* __restrict__ src, uint4* __restrict__ dst, int n8) {
    int i = blockIdx.x * blockDim.x + threadIdx.x;
    if (i >= n8) return;
    float4 a = src[i * 2], b = src[i * 2 + 1];
    U16 v;
    v.h2[0] = __float22half2_rn(make_float2(a.x, a.y));
    v.h2[1] = __float22half2_rn(make_float2(a.z, a.w));
    v.h2[2] = __float22half2_rn(make_float2(b.x, b.y));
    v.h2[3] = __float22half2_rn(make_float2(b.z, b.w));
    dst[i] = v.u;
}

// Pre-swizzle cheb_w (B[256 k][128 h] fp32) into per-lane MFMA B-fragments:
// Bfrag[(kk*8+ht)*64+lane] = 8 halfs B[kk*32+(lane>>4)*8+j][ht*16+(lane&15)]
__global__ void make_bfrag(const float* __restrict__ W, uint4* __restrict__ bfrag) {
    int t = blockIdx.x * blockDim.x + threadIdx.x;   // 0..4095
    if (t >= 8 * 8 * 64) return;
    int lane = t & 63;
    int ht = (t >> 6) & 7;
    int kk = t >> 9;
    int h = ht * 16 + (lane & 15);
    int kb = kk * 32 + (lane >> 4) * 8;
    U16 v;
#pragma unroll
    for (int j = 0; j < 4; ++j) {
        float a = W[(kb + 2 * j) * HDIM + h];
        float b = W[(kb + 2 * j + 1) * HDIM + h];
        v.h2[j] = __float22half2_rn(make_float2(a, b));
    }
    bfrag[t] = v.u;
}

// Per-block exclusive scan over PADDED degrees ((deg+3)&~3) + block totals.
// Also computes dinv (folded former make_dinv dispatch).
__global__ void scan_local(const int* __restrict__ deg, int* __restrict__ out,
                           int* __restrict__ bsum, float* __restrict__ dinv, int n) {
    __shared__ int buf[1024];
    int tid = threadIdx.x;
    int gid = blockIdx.x * 1024 + tid;
    int d = (gid < n) ? deg[gid] : 0;
    if (gid < n) dinv[gid] = (d > 0) ? rsqrtf((float)d) : 0.f;
    int v = (gid < n) ? ((d + 3) & ~3) : 0;
    int x = v;
    buf[tid] = x;
    __syncthreads();
    for (int off = 1; off < 1024; off <<= 1) {
        int t = (tid >= off) ? buf[tid - off] : 0;
        __syncthreads();
        x += t;
        buf[tid] = x;
        __syncthreads();
    }
    if (gid < n) out[gid] = x - v;
    if (tid == 1023) bsum[blockIdx.x] = x;
}

// Wave-parallel exclusive scan of block sums.
__global__ void scan_bsums(int* bsum, int nb) {
    int lane = threadIdx.x;           // 64 threads
    int carry = 0;
    for (int base = 0; base < nb; base += 64) {
        int i = base + lane;
        int v = (i < nb) ? bsum[i] : 0;
        int x = v;
        for (int off = 1; off < 64; off <<= 1) {
            int t = __shfl_up(x, off, 64);
            if (lane >= off) x += t;
        }
        if (i < nb) bsum[i] = carry + x - v;   // exclusive
        carry += __shfl(x, 63, 64);
    }
}

// rowptr[i]: padded CSR base. cursor permuted: cur[(i&7)*stride8 + (i>>3)].
// rowptr[n] = EXACT padded total.
__global__ void scan_finish(int* __restrict__ rowptr, const int* __restrict__ bsum,
                            const int* __restrict__ deg, int* __restrict__ cursor,
                            int n, int stride8) {
    int i = blockIdx.x * blockDim.x + threadIdx.x;
    if (i < n) {
        int v = rowptr[i] + bsum[i >> 10];
        rowptr[i] = v;
        cursor[(i & 7) * stride8 + (i >> 3)] = v;
        if (i == n - 1) rowptr[n] = v + ((deg[i] + 3) & ~3);
    }
}

// XCD-owned scatter: grid = 8 * ceil(E/256); xcd = blockIdx&7 (round-robin
// heuristic). Every epk line + cursor written by ONE XCD.
__global__ void scatter_xcd(const int* __restrict__ row, const int* __restrict__ col,
                            const float* __restrict__ dinv, int* __restrict__ cursor,
                            int2* __restrict__ epk, int E, int stride8) {
    int xcd = blockIdx.x & 7;
    int e = (blockIdx.x >> 3) * blockDim.x + threadIdx.x;
    if (e < E) {
        int r = row[e];
        if ((r & 7) == xcd) {
            int c = col[e];
            int p = atomicAdd(&cursor[xcd * stride8 + (r >> 3)], 1);
            float w = -dinv[r] * dinv[c];   // L_hat = -D^-1/2 A D^-1/2
            epk[p] = make_int2(c, __float_as_int(w));
        }
    }
}

// 8 rows/wave, 8 lanes/row, 16B (8 halfs) per lane, fp32 accumulate.
// Padded CSR: (e-s)%4 == 0, pad slots (col=0,w=0).
// 2-deep pipeline: descriptors prefetched 2 iters ahead, gathers issued 1
// iter ahead -> iter i's FMAs overlap iter i+1's gathers.
__global__ __launch_bounds__(256) void spmm_h(
        const int* __restrict__ rowptr, const int2* __restrict__ epk,
        const uint4* __restrict__ in8, const uint4* __restrict__ prev8,
        float scale, uint4* __restrict__ out8, int n) {
    int lane = threadIdx.x & 63;
    int wid = (blockIdx.x * blockDim.x + threadIdx.x) >> 6;
    int li = lane & 7, g = lane >> 3;
    int r = wid * 8 + g;
    if (r >= n) return;
    int s = rowptr[r], e = rowptr[r + 1];

    U16 pv;
    if (prev8) pv.u = prev8[(size_t)r * 8 + li];   // in flight across the loop

    float acc[8];
#pragma unroll
    for (int j = 0; j < 8; ++j) acc[j] = 0.f;

    if (s < e) {
        int2 mc[4], mn[4];
        U16 vc[4];
#pragma unroll
        for (int j = 0; j < 4; ++j) mc[j] = epk[s + j];        // iter0 desc
#pragma unroll
        for (int j = 0; j < 4; ++j) vc[j].u = in8[(size_t)mc[j].x * 8 + li];  // iter0 gathers
        if (s + 4 < e) {
#pragma unroll
            for (int j = 0; j < 4; ++j) mn[j] = epk[s + 4 + j]; // iter1 desc
        }
        for (int p = s;;) {
            bool more = p + 4 < e;
            bool more2 = p + 8 < e;
            U16 vn[4];
            int2 m2[4];
            if (more) {                                         // iter i+1 gathers
#pragma unroll
                for (int j = 0; j < 4; ++j) vn[j].u = in8[(size_t)mn[j].x * 8 + li];
            }
            if (more2) {                                        // iter i+2 desc
#pragma unroll
                for (int j = 0; j < 4; ++j) m2[j] = epk[p + 8 + j];
            }
            float w0 = __int_as_float(mc[0].y), w1 = __int_as_float(mc[1].y);
            float w2 = __int_as_float(mc[2].y), w3 = __int_as_float(mc[3].y);
#pragma unroll
            for (int j = 0; j < 4; ++j) {
                float2 f0 = __half22float2(vc[0].h2[j]);
                float2 f1 = __half22float2(vc[1].h2[j]);
                float2 f2 = __half22float2(vc[2].h2[j]);
                float2 f3 = __half22float2(vc[3].h2[j]);
                acc[2 * j]     = fmaf(w0, f0.x, acc[2 * j]);
                acc[2 * j + 1] = fmaf(w0, f0.y, acc[2 * j + 1]);
                acc[2 * j]     = fmaf(w1, f1.x, acc[2 * j]);
                acc[2 * j + 1] = fmaf(w1, f1.y, acc[2 * j + 1]);
                acc[2 * j]     = fmaf(w2, f2.x, acc[2 * j]);
                acc[2 * j + 1] = fmaf(w2, f2.y, acc[2 * j + 1]);
                acc[2 * j]     = fmaf(w3, f3.x, acc[2 * j]);
                acc[2 * j + 1] = fmaf(w3, f3.y, acc[2 * j + 1]);
            }
            if (!more) break;
#pragma unroll
            for (int j = 0; j < 4; ++j) {
                mc[j] = mn[j];
                mn[j] = m2[j];   // garbage when !more2; never gathered then
                vc[j] = vn[j];
            }
            p += 4;
        }
    }

    float res[8];
    if (prev8) {
#pragma unroll
        for (int t = 0; t < 4; ++t) {
            float2 f = __half22float2(pv.h2[t]);
            res[2 * t]     = fmaf(scale, acc[2 * t], -f.x);
            res[2 * t + 1] = fmaf(scale, acc[2 * t + 1], -f.y);
        }
    } else {
#pragma unroll
        for (int j = 0; j < 8; ++j) res[j] = scale * acc[j];
    }
    U16 ru;
#pragma unroll
    for (int t = 0; t < 4; ++t)
        ru.h2[t] = __float22half2_rn(make_float2(res[2 * t], res[2 * t + 1]));
    out8[(size_t)r * 8 + li] = ru.u;
}

__device__ inline float tanh_fast(float x) {
    x = fmaxf(-10.f, fminf(10.f, x));
    float e = __expf(2.f * x);
    return (e - 1.f) / (e + 1.f);
}

// MFMA GEMM + tanh + final dot. Block = 256 thr = 4 waves; wave = 16 nodes x
// 128 h (8 tiles of 16x16, K=32/step, 8 steps over K=256). LDS-free.
__global__ __launch_bounds__(256) void gemm_mfma(
        const uint4* __restrict__ tx0, const uint4* __restrict__ tx1,
        const uint4* __restrict__ tx2, const uint4* __restrict__ tx3,
        const uint4* __restrict__ bfrag,
        const float* __restrict__ cheb_b, const float* __restrict__ fw,
        const float* __restrict__ fb, float* __restrict__ out, int n) {
    int tid = threadIdx.x;
    int lane = tid & 63;
    int wave = tid >> 6;
    int q = lane >> 4, m = lane & 15;
    int node_base = blockIdx.x * 64 + wave * 16;
    int node = node_base + m;
    size_t nd = (node < n) ? (size_t)node : 0;   // clamp; store is guarded

    f32x4 acc[8];
#pragma unroll
    for (int t = 0; t < 8; ++t) acc[t] = (f32x4){0.f, 0.f, 0.f, 0.f};

    const uint4* txs[4] = {tx0, tx1, tx2, tx3};
#pragma unroll
    for (int kk = 0; kk < 8; ++kk) {
        U16 av;
        av.u = txs[kk >> 1][nd * 8 + (kk & 1) * 4 + q];
#pragma unroll
        for (int ht = 0; ht < 8; ++ht) {
            U16 bv;
            bv.u = bfrag[(kk * 8 + ht) * 64 + lane];
            acc[ht] = __builtin_amdgcn_mfma_f32_16x16x32_f16(av.h8, bv.h8, acc[ht], 0, 0, 0);
        }
    }

    float s[4] = {0.f, 0.f, 0.f, 0.f};
#pragma unroll
    for (int ht = 0; ht < 8; ++ht) {
        int h = ht * 16 + m;
        float cb = cheb_b[h];
        float fv = fw[h];
#pragma unroll
        for (int r = 0; r < 4; ++r)
            s[r] = fmaf(tanh_fast(acc[ht][r] + cb), fv, s[r]);
    }
#pragma unroll
    for (int r = 0; r < 4; ++r) {
        for (int msk = 1; msk < 16; msk <<= 1)
            s[r] += __shfl_xor(s[r], msk, 64);
    }
    if (m == 0) {
        float fb0 = fb[0];
#pragma unroll
        for (int r = 0; r < 4; ++r) {
            int o = node_base + q * 4 + r;
            if (o < n) out[o] = s[r] + fb0;
        }
    }
}

extern "C" void kernel_launch(void* const* d_in, const int* in_sizes, int n_in,
                              void* d_out, int out_size, void* d_ws, size_t ws_size,
                              hipStream_t stream) {
    const float* features = (const float*)d_in[0];
    const int*   edge_index = (const int*)d_in[1];
    const float* cheb_w  = (const float*)d_in[2];
    const float* cheb_b  = (const float*)d_in[3];
    const float* final_w = (const float*)d_in[4];
    const float* final_b = (const float*)d_in[5];
    int N = in_sizes[0] / FIN;
    int E = in_sizes[1] / 2;
    const int* row = edge_index;        // edge_index[0, :]
    const int* col = edge_index + E;    // edge_index[1, :]
    int E_pad = E + 4 * N;              // allocation bound on padded edges
    int stride8 = (N + 7) / 8;

    char* p = (char*)d_ws;
    auto alloc = [&](size_t bytes) {
        char* r = p;
        p += (bytes + 255) & ~(size_t)255;
        return r;
    };
    // deg + epk adjacent: one memset zeroes both (epk pad slots = col 0, w 0)
    int*   deg    = (int*)alloc((size_t)N * 4);
    int2*  epk    = (int2*)alloc((size_t)E_pad * 8);
    size_t zero_bytes = (char*)(epk + E_pad) - (char*)deg;
    float* dinv   = (float*)alloc((size_t)N * 4);
    int*   rowptr = (int*)alloc((size_t)(N + 1) * 4);
    int*   cursor = (int*)alloc((size_t)(stride8 * 8) * 4);
    int*   bsum   = (int*)alloc(1024 * 4);
    uint4* feath  = (uint4*)alloc((size_t)N * FIN * 2);   // fp16 rows
    uint4* tx1h   = (uint4*)alloc((size_t)N * FIN * 2);
    uint4* tx2h   = (uint4*)alloc((size_t)N * FIN * 2);
    uint4* tx3h   = (uint4*)alloc((size_t)N * FIN * 2);
    uint4* bfrag  = (uint4*)alloc(4096 * 16);             // 64 KB B fragments

    hipMemsetAsync(deg, 0, zero_bytes, stream);
    count_deg<<<(E + 255) / 256, 256, 0, stream>>>(row, deg, E);
    int n8 = N * FIN / 8;
    cvt_feat<<<(n8 + 255) / 256, 256, 0, stream>>>((const float4*)features, feath, n8);
    make_bfrag<<<16, 256, 0, stream>>>(cheb_w, bfrag);
    int nb = (N + 1023) / 1024;
    scan_local<<<nb, 1024, 0, stream>>>(deg, rowptr, bsum, dinv, N);
    scan_bsums<<<1, 64, 0, stream>>>(bsum, nb);
    scan_finish<<<(N + 255) / 256, 256, 0, stream>>>(rowptr, bsum, deg, cursor, N, stride8);
    int eb = (E + 255) / 256;
    scatter_xcd<<<eb * 8, 256, 0, stream>>>(row, col, dinv, cursor, epk, E, stride8);

    int spmm_blocks = (((N + 7) / 8) * 64 + 255) / 256;
    // Tx1 = L_hat @ x
    spmm_h<<<spmm_blocks, 256, 0, stream>>>(rowptr, epk, feath, nullptr, 1.f, tx1h, N);
    // Tx2 = 2 * L_hat @ Tx1 - Tx0
    spmm_h<<<spmm_blocks, 256, 0, stream>>>(rowptr, epk, tx1h, feath, 2.f, tx2h, N);
    // Tx3 = 2 * L_hat @ Tx2 - Tx1
    spmm_h<<<spmm_blocks, 256, 0, stream>>>(rowptr, epk, tx2h, tx1h, 2.f, tx3h, N);

    gemm_mfma<<<(N + 63) / 64, 256, 0, stream>>>(feath, tx1h, tx2h, tx3h, bfrag,
                                                 cheb_b, final_w, final_b,
                                                 (float*)d_out, N);
}